// Round 1
// baseline (15647.482 us; speedup 1.0000x reference)
//
#include <hip/hip_runtime.h>
#include <stdint.h>

#define B_ 32
#define T_ 2048
#define H_ 256
#define E_ 256
#define M_ 64
#define L_ 256
#define G_ 1024

#define NS_ 32      // hidden-dim slices (blocks per group)
#define NG_ 8       // batch groups
#define CNT_PAD 32  // ints per counter slot (128B line each)

__device__ __forceinline__ float sig_fast(float x){ return 1.f/(1.f+__expf(-x)); }
__device__ __forceinline__ float tanh_fast(float x){ return 2.f/(1.f+__expf(-2.f*x)) - 1.f; }
__device__ __forceinline__ float dot4(float4 a, float4 b){
  return fmaf(a.x,b.x, fmaf(a.y,b.y, fmaf(a.z,b.z, a.w*b.w)));
}

// ---------------- prep kernels ----------------
__global__ void prep_wdc(const float* __restrict__ a, const float* __restrict__ b,
                         float* __restrict__ o){
  int i = blockIdx.x*256 + threadIdx.x;   // 262144 total
  o[i] = a[i] + b[i];
}

__global__ void prep_small(const float* __restrict__ Wp, const float* __restrict__ bp,
                           const float* __restrict__ Wihe, const float* __restrict__ bihe,
                           const float* __restrict__ bhhe, const float* __restrict__ bihd,
                           const float* __restrict__ bhhd, const float* __restrict__ Wq,
                           float* __restrict__ Wc0, float* __restrict__ Wc1,
                           float* __restrict__ bc, float* __restrict__ bdc,
                           float* __restrict__ WqT){
  int idx = blockIdx.x*256 + threadIdx.x;
  if (idx < 16384){                 // WqT[m][k] = Wq[k][m]
    int m = idx >> 8, k = idx & 255;
    WqT[m*256 + k] = Wq[k*64 + m];
  } else if (idx < 16384 + 1024){   // per-gate-row fused input coeffs
    int j = idx - 16384;
    const float* wr = Wihe + j*256;
    float a0=0.f, a1=0.f, ab=0.f;
    for (int e=0;e<256;e++){
      float w = wr[e];
      a0 = fmaf(Wp[e],     w, a0);
      a1 = fmaf(Wp[256+e], w, a1);
      ab = fmaf(bp[e],     w, ab);
    }
    Wc0[j] = a0; Wc1[j] = a1;
    bc[j]  = ab + bihe[j] + bhhe[j];
    bdc[j] = bihd[j] + bhhd[j];
  }
}

// ---------------- encoder LSTM (persistent, flag-synced) ----------------
__global__ __launch_bounds__(256) void enc_kernel(
    const float* __restrict__ seq, const int* __restrict__ slen,
    const float* __restrict__ Whh,
    const float* __restrict__ Wc0, const float* __restrict__ Wc1,
    const float* __restrict__ bc,
    float* __restrict__ h_all, float* __restrict__ cT, int* __restrict__ cnt)
{
  const int tid = threadIdx.x;
  const int grp = blockIdx.x & 7;
  const int slice = blockIdx.x >> 3;
  const int rp = tid >> 4, kc = tid & 15;     // row-pair, k-chunk
  const int r0 = rp*2, r1 = r0+1;             // local rows 0..31 = gate*8+e
  const int j0 = ((r0>>3)<<8) + slice*8 + (r0&7);
  const int j1 = ((r1>>3)<<8) + slice*8 + (r1&7);

  float4 w0[4], w1[4];                        // 32 weights/thread, bank-friendly k map
#pragma unroll
  for (int u=0;u<4;u++){
    w0[u] = *(const float4*)(Whh + j0*256 + u*64 + kc*4);
    w1[u] = *(const float4*)(Whh + j1*256 + u*64 + kc*4);
  }
  float c00=0.f,c01=0.f,cb0=0.f,c10=0.f,c11=0.f,cb1=0.f;
  if (kc==0){ c00=Wc0[j0]; c01=Wc1[j0]; cb0=bc[j0];
              c10=Wc0[j1]; c11=Wc1[j1]; cb1=bc[j1]; }

  __shared__ float hbuf[4][256];
  __shared__ float gbuf[4][32];
  __shared__ float sbuf[4][2];

  float creg = 0.f;                           // c-state: threads 0..31 own (batch, elem)
  int myb = 0, mylen = -1;
  const int ub = tid>>3, ue = tid&7;
  if (tid<32){ myb = grp + 8*ub; mylen = slen[myb]; }
  const int sb = tid>>6, sk = tid&63;
  const int stage_b = grp + 8*sb;

  for (int t=0; t<T_; ++t){
    if (t>0){
      if (tid==0){
        int* f = cnt + ((size_t)(t-1)*NG_ + grp)*CNT_PAD;
        while (__hip_atomic_load(f, __ATOMIC_ACQUIRE, __HIP_MEMORY_SCOPE_AGENT) < NS_) {}
      }
      __syncthreads();
    }
    // stage h_{t-1} (4 batches) + per-step inputs
    float4 hv;
    if (t==0){ hv.x=0.f; hv.y=0.f; hv.z=0.f; hv.w=0.f; }
    else hv = *(const float4*)(h_all + ((size_t)(t-1)*B_ + stage_b)*H_ + sk*4);
    *(float4*)(&hbuf[sb][sk*4]) = hv;
    if (tid<8) sbuf[tid>>1][tid&1] = seq[((size_t)(grp+8*(tid>>1))*T_ + t)*2 + (tid&1)];
    __syncthreads();

#pragma unroll
    for (int i=0;i<4;i++){
      float a0=0.f, a1=0.f;
#pragma unroll
      for (int u=0;u<4;u++){
        float4 h4 = *(const float4*)(&hbuf[i][u*64 + kc*4]);
        a0 = fmaf(w0[u].x,h4.x,a0); a0 = fmaf(w0[u].y,h4.y,a0);
        a0 = fmaf(w0[u].z,h4.z,a0); a0 = fmaf(w0[u].w,h4.w,a0);
        a1 = fmaf(w1[u].x,h4.x,a1); a1 = fmaf(w1[u].y,h4.y,a1);
        a1 = fmaf(w1[u].z,h4.z,a1); a1 = fmaf(w1[u].w,h4.w,a1);
      }
#pragma unroll
      for (int off=1; off<16; off<<=1){
        a0 += __shfl_xor(a0, off);
        a1 += __shfl_xor(a1, off);
      }
      if (kc==0){
        float s0 = sbuf[i][0], s1 = sbuf[i][1];
        gbuf[i][r0] = fmaf(s0,c00, fmaf(s1,c01, a0 + cb0));
        gbuf[i][r1] = fmaf(s0,c10, fmaf(s1,c11, a1 + cb1));
      }
    }
    __syncthreads();
    if (tid<32){
      float gi=gbuf[ub][ue], gf=gbuf[ub][8+ue], gg=gbuf[ub][16+ue], go=gbuf[ub][24+ue];
      creg = sig_fast(gf)*creg + sig_fast(gi)*tanh_fast(gg);
      float h = sig_fast(go)*tanh_fast(creg);
      __hip_atomic_store(h_all + ((size_t)t*B_ + myb)*H_ + slice*8 + ue, h,
                         __ATOMIC_RELAXED, __HIP_MEMORY_SCOPE_AGENT);
      if (t == mylen-1) cT[myb*H_ + slice*8 + ue] = creg;
    }
    __syncthreads();
    if (tid==0)
      __hip_atomic_fetch_add(cnt + ((size_t)t*NG_ + grp)*CNT_PAD, 1,
                             __ATOMIC_RELEASE, __HIP_MEMORY_SCOPE_AGENT);
  }
}

// ---------------- decoder LSTM (x == h, folded weights) ----------------
__global__ __launch_bounds__(256) void dec_kernel(
    const int* __restrict__ slen,
    const float* __restrict__ Wdc, const float* __restrict__ bdc,
    const float* __restrict__ h_all, const float* __restrict__ cT,
    float* __restrict__ h2_all, int* __restrict__ cnt)
{
  const int tid = threadIdx.x;
  const int grp = blockIdx.x & 7;
  const int slice = blockIdx.x >> 3;
  const int rp = tid >> 4, kc = tid & 15;
  const int r0 = rp*2, r1 = r0+1;
  const int j0 = ((r0>>3)<<8) + slice*8 + (r0&7);
  const int j1 = ((r1>>3)<<8) + slice*8 + (r1&7);
  float4 w0[4], w1[4];
#pragma unroll
  for (int u=0;u<4;u++){
    w0[u] = *(const float4*)(Wdc + j0*256 + u*64 + kc*4);
    w1[u] = *(const float4*)(Wdc + j1*256 + u*64 + kc*4);
  }
  float cb0=0.f, cb1=0.f;
  if (kc==0){ cb0=bdc[j0]; cb1=bdc[j1]; }

  __shared__ float hbuf[4][256];
  __shared__ float gbuf[4][32];

  float creg = 0.f; int myb = 0;
  const int ub = tid>>3, ue = tid&7;
  if (tid<32){ myb = grp + 8*ub; creg = cT[myb*H_ + slice*8 + ue]; }
  const int sb = tid>>6, sk = tid&63;
  const int stage_b = grp + 8*sb;
  const int stage_len = slen[stage_b];

  for (int s=0; s<L_; ++s){
    if (s>0){
      if (tid==0){
        int* f = cnt + ((size_t)(s-1)*NG_ + grp)*CNT_PAD;
        while (__hip_atomic_load(f, __ATOMIC_ACQUIRE, __HIP_MEMORY_SCOPE_AGENT) < NS_) {}
      }
      __syncthreads();
    }
    const float* src = (s==0)
        ? (h_all  + ((size_t)(stage_len-1)*B_ + stage_b)*H_)
        : (h2_all + ((size_t)(s-1)*B_ + stage_b)*H_);
    *(float4*)(&hbuf[sb][sk*4]) = *(const float4*)(src + sk*4);
    __syncthreads();

#pragma unroll
    for (int i=0;i<4;i++){
      float a0=0.f, a1=0.f;
#pragma unroll
      for (int u=0;u<4;u++){
        float4 h4 = *(const float4*)(&hbuf[i][u*64 + kc*4]);
        a0 = fmaf(w0[u].x,h4.x,a0); a0 = fmaf(w0[u].y,h4.y,a0);
        a0 = fmaf(w0[u].z,h4.z,a0); a0 = fmaf(w0[u].w,h4.w,a0);
        a1 = fmaf(w1[u].x,h4.x,a1); a1 = fmaf(w1[u].y,h4.y,a1);
        a1 = fmaf(w1[u].z,h4.z,a1); a1 = fmaf(w1[u].w,h4.w,a1);
      }
#pragma unroll
      for (int off=1; off<16; off<<=1){
        a0 += __shfl_xor(a0, off);
        a1 += __shfl_xor(a1, off);
      }
      if (kc==0){ gbuf[i][r0] = a0 + cb0; gbuf[i][r1] = a1 + cb1; }
    }
    __syncthreads();
    if (tid<32){
      float gi=gbuf[ub][ue], gf=gbuf[ub][8+ue], gg=gbuf[ub][16+ue], go=gbuf[ub][24+ue];
      creg = sig_fast(gf)*creg + sig_fast(gi)*tanh_fast(gg);
      float h = sig_fast(go)*tanh_fast(creg);
      __hip_atomic_store(h2_all + ((size_t)s*B_ + myb)*H_ + slice*8 + ue, h,
                         __ATOMIC_RELAXED, __HIP_MEMORY_SCOPE_AGENT);
    }
    __syncthreads();
    if (tid==0)
      __hip_atomic_fetch_add(cnt + ((size_t)s*NG_ + grp)*CNT_PAD, 1,
                             __ATOMIC_RELEASE, __HIP_MEMORY_SCOPE_AGENT);
  }
}

// ---------------- kproj = masked(enc) @ Wk + bk ----------------
__global__ __launch_bounds__(256) void kproj_kernel(
    const float* __restrict__ h_all, const int* __restrict__ slen,
    const float* __restrict__ Wk, const float* __restrict__ bk,
    float* __restrict__ kp)
{
  __shared__ float wk[256*64];   // 64 KB
  const int tid = threadIdx.x;
  const int b = blockIdx.x >> 4, tc = blockIdx.x & 15;
  const int t0 = tc*128;
#pragma unroll
  for (int i=0;i<16;i++){
    int idx = tid + i*256;
    *(float4*)(&wk[idx*4]) = *(const float4*)(Wk + idx*4);
  }
  __syncthreads();
  const int tp = tid>>2, mc = (tid&3)*16;
  const int ta = t0 + tp*2, tb = ta+1;
  const int len = slen[b];
  const bool va = ta < len, vb = tb < len;
  const float* ha = h_all + ((size_t)ta*B_ + b)*H_;
  const float* hb = h_all + ((size_t)tb*B_ + b)*H_;
  float4 A[4], Bv[4];
#pragma unroll
  for (int u=0;u<4;u++){ A[u].x=A[u].y=A[u].z=A[u].w=0.f; Bv[u]=A[u]; }

  for (int k4=0;k4<64;k4++){
    float xa[4], xb[4];
    if (va){ float4 v = *(const float4*)(ha + k4*4); xa[0]=v.x; xa[1]=v.y; xa[2]=v.z; xa[3]=v.w; }
    else   { xa[0]=xa[1]=xa[2]=xa[3]=0.f; }
    if (vb){ float4 v = *(const float4*)(hb + k4*4); xb[0]=v.x; xb[1]=v.y; xb[2]=v.z; xb[3]=v.w; }
    else   { xb[0]=xb[1]=xb[2]=xb[3]=0.f; }
#pragma unroll
    for (int j=0;j<4;j++){
      const float* wr = &wk[(k4*4+j)*64 + mc];
#pragma unroll
      for (int u=0;u<4;u++){
        float4 wv = *(const float4*)(wr + u*4);
        A[u].x  = fmaf(xa[j],wv.x,A[u].x);  A[u].y  = fmaf(xa[j],wv.y,A[u].y);
        A[u].z  = fmaf(xa[j],wv.z,A[u].z);  A[u].w  = fmaf(xa[j],wv.w,A[u].w);
        Bv[u].x = fmaf(xb[j],wv.x,Bv[u].x); Bv[u].y = fmaf(xb[j],wv.y,Bv[u].y);
        Bv[u].z = fmaf(xb[j],wv.z,Bv[u].z); Bv[u].w = fmaf(xb[j],wv.w,Bv[u].w);
      }
    }
  }
#pragma unroll
  for (int u=0;u<4;u++){
    float4 bkv = *(const float4*)(bk + mc + u*4);
    float4 ra, rb;
    ra.x = va ? A[u].x+bkv.x : bkv.x;  ra.y = va ? A[u].y+bkv.y : bkv.y;
    ra.z = va ? A[u].z+bkv.z : bkv.z;  ra.w = va ? A[u].w+bkv.w : bkv.w;
    rb.x = vb ? Bv[u].x+bkv.x : bkv.x; rb.y = vb ? Bv[u].y+bkv.y : bkv.y;
    rb.z = vb ? Bv[u].z+bkv.z : bkv.z; rb.w = vb ? Bv[u].w+bkv.w : bkv.w;
    *(float4*)(kp + ((size_t)b*T_+ta)*M_ + mc + u*4) = ra;
    *(float4*)(kp + ((size_t)b*T_+tb)*M_ + mc + u*4) = rb;
  }
}

// ---------------- attention: q, scores, softmax, write probs ----------------
__global__ __launch_bounds__(256) void attn_kernel(
    const float* __restrict__ h2_all, const float* __restrict__ kp,
    const float* __restrict__ WqT, const float* __restrict__ bq,
    const int* __restrict__ slen, float* __restrict__ out)
{
  const int tid = threadIdx.x;
  const int b = blockIdx.x >> 5, scg = blockIdx.x & 31;
  const int s0 = scg*8;
  __shared__ float qL[8][64];
  __shared__ float red[8][4];
  const int wid = tid>>6, lane = tid&63;

  { // q = h2 @ Wq + bq  (two m's per thread)
    const int j = tid>>5, mh = tid&31;
    const float* hr = h2_all + ((size_t)(s0+j)*B_ + b)*H_;
    const float* wa = WqT + (size_t)mh*256;
    const float* wb = WqT + (size_t)(mh+32)*256;
    float a0=0.f, a1=0.f;
    for (int k4=0;k4<64;k4++){
      float4 h4 = *(const float4*)(hr + k4*4);
      float4 v0 = *(const float4*)(wa + k4*4);
      float4 v1 = *(const float4*)(wb + k4*4);
      a0 += dot4(h4,v0);
      a1 += dot4(h4,v1);
    }
    qL[j][mh]    = a0 + bq[mh];
    qL[j][mh+32] = a1 + bq[mh+32];
  }
  __syncthreads();

  const int len = slen[b];
  float sc_[8][8];
#pragma unroll
  for (int ti=0; ti<8; ti++){
    const int t = ti*256 + tid;
    const float* kr = kp + ((size_t)b*T_ + t)*M_;
    float tmp[8];
#pragma unroll
    for (int j=0;j<8;j++) tmp[j]=0.f;
#pragma unroll
    for (int u4=0; u4<4; u4++){
      float4 k0 = *(const float4*)(kr + u4*16);
      float4 k1 = *(const float4*)(kr + u4*16 + 4);
      float4 k2 = *(const float4*)(kr + u4*16 + 8);
      float4 k3 = *(const float4*)(kr + u4*16 + 12);
#pragma unroll
      for (int j=0;j<8;j++){
        const float4* q4 = (const float4*)&qL[j][u4*16];
        tmp[j] += dot4(k0,q4[0]) + dot4(k1,q4[1]) + dot4(k2,q4[2]) + dot4(k3,q4[3]);
      }
    }
    float bias = (t<len) ? 0.f : -1e9f;
#pragma unroll
    for (int j=0;j<8;j++) sc_[ti][j] = fmaf(tmp[j], 0.125f, bias);
  }

  // softmax over t (block-wide), per s
  float mx[8];
#pragma unroll
  for (int j=0;j<8;j++){
    float m = sc_[0][j];
#pragma unroll
    for (int ti=1;ti<8;ti++) m = fmaxf(m, sc_[ti][j]);
#pragma unroll
    for (int off=1; off<64; off<<=1) m = fmaxf(m, __shfl_xor(m, off));
    if (lane==0) red[j][wid] = m;
  }
  __syncthreads();
#pragma unroll
  for (int j=0;j<8;j++)
    mx[j] = fmaxf(fmaxf(red[j][0],red[j][1]), fmaxf(red[j][2],red[j][3]));
  __syncthreads();
#pragma unroll
  for (int j=0;j<8;j++){
    float s = 0.f;
#pragma unroll
    for (int ti=0;ti<8;ti++){
      float e = __expf(sc_[ti][j] - mx[j]);
      sc_[ti][j] = e;
      s += e;
    }
#pragma unroll
    for (int off=1; off<64; off<<=1) s += __shfl_xor(s, off);
    if (lane==0) red[j][wid] = s;
  }
  __syncthreads();
#pragma unroll
  for (int j=0;j<8;j++){
    float r = 1.f/(red[j][0]+red[j][1]+red[j][2]+red[j][3]);
    float* o = out + ((size_t)b*L_ + s0 + j)*T_;
#pragma unroll
    for (int ti=0;ti<8;ti++) o[ti*256 + tid] = sc_[ti][j]*r;
  }
}

// ---------------- host ----------------
extern "C" void kernel_launch(void* const* d_in, const int* in_sizes, int n_in,
                              void* d_out, int out_size, void* d_ws, size_t ws_size,
                              hipStream_t stream) {
  (void)in_sizes; (void)n_in; (void)out_size;
  const float* seq  = (const float*)d_in[0];
  const int*   slen = (const int*)  d_in[1];
  const float* Wp   = (const float*)d_in[3];
  const float* bp   = (const float*)d_in[4];
  const float* Wihe = (const float*)d_in[5];
  const float* Whhe = (const float*)d_in[6];
  const float* bihe = (const float*)d_in[7];
  const float* bhhe = (const float*)d_in[8];
  const float* Wihd = (const float*)d_in[9];
  const float* Whhd = (const float*)d_in[10];
  const float* bihd = (const float*)d_in[11];
  const float* bhhd = (const float*)d_in[12];
  const float* Wq   = (const float*)d_in[13];
  const float* bq   = (const float*)d_in[14];
  const float* Wk   = (const float*)d_in[15];
  const float* bk   = (const float*)d_in[16];
  float* out = (float*)d_out;

  char* p = (char*)d_ws;
  auto take = [&](size_t bytes)->char* {
    char* r = p; p += (bytes + 255) & ~(size_t)255; return r;
  };
  float* h2_all = (float*)take((size_t)L_*B_*H_*4);        // 8 MB
  float* kproj  = (float*)take((size_t)B_*T_*M_*4);        // 16 MB
  float* cT     = (float*)take((size_t)B_*H_*4);
  float* W_dc   = (float*)take((size_t)G_*H_*4);           // 1 MB
  float* Wc0    = (float*)take(G_*4);
  float* Wc1    = (float*)take(G_*4);
  float* bc     = (float*)take(G_*4);
  float* b_dc   = (float*)take(G_*4);
  float* WqT    = (float*)take((size_t)M_*H_*4);
  int*   cnt_e  = (int*)  take((size_t)T_*NG_*CNT_PAD*4);  // 2 MB
  int*   cnt_d  = (int*)  take((size_t)L_*NG_*CNT_PAD*4);  // 256 KB

  size_t used = (size_t)(p - (char*)d_ws);
  float* h_all;
  if (ws_size >= used + (size_t)T_*B_*H_*4) {
    h_all = (float*)take((size_t)T_*B_*H_*4);              // 64 MB
  } else {
    // d_out is exactly T_*B_*H_ floats; h_all is dead before attention writes out.
    h_all = out;
  }

  hipMemsetAsync(cnt_e, 0, (size_t)T_*NG_*CNT_PAD*4, stream);
  hipMemsetAsync(cnt_d, 0, (size_t)L_*NG_*CNT_PAD*4, stream);

  prep_wdc  <<<G_*H_/256, 256, 0, stream>>>(Wihd, Whhd, W_dc);
  prep_small<<<68, 256, 0, stream>>>(Wp, bp, Wihe, bihe, bhhe, bihd, bhhd, Wq,
                                     Wc0, Wc1, bc, b_dc, WqT);
  enc_kernel<<<NS_*NG_, 256, 0, stream>>>(seq, slen, Whhe, Wc0, Wc1, bc,
                                          h_all, cT, cnt_e);
  kproj_kernel<<<B_*16, 256, 0, stream>>>(h_all, slen, Wk, bk, kproj);
  dec_kernel<<<NS_*NG_, 256, 0, stream>>>(slen, W_dc, b_dc, h_all, cT,
                                          h2_all, cnt_d);
  attn_kernel<<<B_*32, 256, 0, stream>>>(h2_all, kproj, WqT, bq, slen, out);
}

// Round 3
// 7475.069 us; speedup vs baseline: 2.0933x; 2.0933x over previous
//
#include <hip/hip_runtime.h>
#include <stdint.h>

#define B_ 32
#define T_ 2048
#define H_ 256
#define M_ 64
#define L_ 256
#define G4_ 1024     // 4*H gate rows

#define NG_ 8        // batch groups (4 batches each)
#define NSL_ 16      // hidden slices per group
#define EPT_ 16      // h elements per slice

#define SENT_ 0xFFFFFFFFu   // per-dword sentinel (NaN pattern; h is never NaN)

__device__ __forceinline__ float sig_fast(float x){ return 1.f/(1.f+__expf(-x)); }
__device__ __forceinline__ float tanh_fast(float x){ return 2.f/(1.f+__expf(-2.f*x)) - 1.f; }
__device__ __forceinline__ float dot4(float4 a, float4 b){
  return fmaf(a.x,b.x, fmaf(a.y,b.y, fmaf(a.z,b.z, a.w*b.w)));
}

// ---------------- prep kernels ----------------
__global__ void prep_wdc(const float* __restrict__ a, const float* __restrict__ b,
                         float* __restrict__ o){
  int i = blockIdx.x*256 + threadIdx.x;
  o[i] = a[i] + b[i];
}

__global__ void prep_small(const float* __restrict__ Wp, const float* __restrict__ bp,
                           const float* __restrict__ Wihe, const float* __restrict__ bihe,
                           const float* __restrict__ bhhe, const float* __restrict__ bihd,
                           const float* __restrict__ bhhd, const float* __restrict__ Wq,
                           float* __restrict__ Wc0, float* __restrict__ Wc1,
                           float* __restrict__ bc, float* __restrict__ bdc,
                           float* __restrict__ WqT){
  int idx = blockIdx.x*256 + threadIdx.x;
  if (idx < 16384){                 // WqT[m][k] = Wq[k][m]
    int m = idx >> 8, k = idx & 255;
    WqT[m*256 + k] = Wq[k*64 + m];
  } else if (idx < 16384 + 1024){   // fused input coeffs per gate row
    int j = idx - 16384;
    const float* wr = Wihe + j*256;
    float a0=0.f, a1=0.f, ab=0.f;
    for (int e=0;e<256;e++){
      float w = wr[e];
      a0 = fmaf(Wp[e],     w, a0);
      a1 = fmaf(Wp[256+e], w, a1);
      ab = fmaf(bp[e],     w, ab);
    }
    Wc0[j] = a0; Wc1[j] = a1;
    bc[j]  = ab + bihe[j] + bhhe[j];
    bdc[j] = bihd[j] + bhhd[j];
  }
}

// poll 8 bytes of h-state until both dwords are non-sentinel (relaxed agent load;
// value-carried dependency, no fence needed; agent scope => cross-XCD coherent)
__device__ __forceinline__ float2 poll8(const float* src){
  unsigned long long u;
  do {
    u = __hip_atomic_load((const unsigned long long*)src,
                          __ATOMIC_RELAXED, __HIP_MEMORY_SCOPE_AGENT);
  } while ((unsigned)u == SENT_ || (unsigned)(u>>32) == SENT_);
  return __builtin_bit_cast(float2, u);
}

// ---------------- encoder LSTM (persistent, data-sentinel synced) ----------------
__global__ __launch_bounds__(1024) void enc_kernel(
    const float* __restrict__ seq, const int* __restrict__ slen,
    const float* __restrict__ Whh,
    const float* __restrict__ Wc0, const float* __restrict__ Wc1,
    const float* __restrict__ bc,
    float* __restrict__ h_all, float* __restrict__ cT)
{
  const int tid = threadIdx.x;
  const int grp = blockIdx.x & 7, slice = blockIdx.x >> 3;
  const int rp = tid >> 4, kc = tid & 15;
  const int j = ((rp >> 4) << 8) + slice*EPT_ + (rp & 15);   // gate*256 + slice*16 + elem
  float4 w0 = *(const float4*)(Whh + (size_t)j*256 +   0 + kc*4);
  float4 w1 = *(const float4*)(Whh + (size_t)j*256 +  64 + kc*4);
  float4 w2 = *(const float4*)(Whh + (size_t)j*256 + 128 + kc*4);
  float4 w3 = *(const float4*)(Whh + (size_t)j*256 + 192 + kc*4);
  float c0 = Wc0[j], c1 = Wc1[j], cbv = bc[j];

  __shared__ float hbuf[4][256];
  __shared__ float sbuf[4][2];
  __shared__ float gbuf[4][64];

  const int ub = tid >> 4, ue = tid & 15;       // update mapping (tid<64)
  float creg = 0.f;
  int myb = 0, mylen = -1;
  if (tid < 64){ myb = grp + 8*ub; mylen = slen[myb]; }

  const int tb = tid >> 7, kp = tid & 127;      // staging (tid<512): batch tb, elems 2kp..2kp+1
  const int stage_b = grp + 8*tb;

  for (int t = 0; t < T_; ++t){
    // ---- stage h_{t-1} (poll own 8 bytes) + per-step seq inputs ----
    if (tid < 512){
      if (t == 0){
        *(float2*)&hbuf[tb][kp*2] = make_float2(0.f, 0.f);
      } else {
        *(float2*)&hbuf[tb][kp*2] =
            poll8(h_all + ((size_t)(t-1)*B_ + stage_b)*H_ + kp*2);
      }
      if (tid < 8) sbuf[tid>>1][tid&1] = seq[((size_t)(grp + 8*(tid>>1))*T_ + t)*2 + (tid&1)];
    }
    __syncthreads();  // B1: hbuf/sbuf ready

    // ---- compute: one gate row per thread, K split over 16 lanes ----
#pragma unroll
    for (int i = 0; i < 4; ++i){
      float4 h0 = *(const float4*)&hbuf[i][       kc*4];
      float4 h1 = *(const float4*)&hbuf[i][ 64 + kc*4];
      float4 h2 = *(const float4*)&hbuf[i][128 + kc*4];
      float4 h3 = *(const float4*)&hbuf[i][192 + kc*4];
      float a = dot4(w0,h0) + dot4(w1,h1) + dot4(w2,h2) + dot4(w3,h3);
#pragma unroll
      for (int off = 1; off < 16; off <<= 1) a += __shfl_xor(a, off);
      if (kc == 0)
        gbuf[i][rp] = fmaf(sbuf[i][0], c0, fmaf(sbuf[i][1], c1, a + cbv));
    }
    __syncthreads();  // B2: gbuf ready

    // ---- update + publish (tid<64: 4 batches x 16 elems) ----
    if (tid < 64){
      float gi = gbuf[ub][      ue];
      float gf = gbuf[ub][16 + ue];
      float gg = gbuf[ub][32 + ue];
      float go = gbuf[ub][48 + ue];
      creg = sig_fast(gf)*creg + sig_fast(gi)*tanh_fast(gg);
      float h = sig_fast(go)*tanh_fast(creg);
      __hip_atomic_store(h_all + ((size_t)t*B_ + myb)*H_ + slice*EPT_ + ue, h,
                         __ATOMIC_RELAXED, __HIP_MEMORY_SCOPE_AGENT);
      if (t == mylen - 1) cT[myb*H_ + slice*EPT_ + ue] = creg;
    }
    // no barrier needed: next-iter staging writes hbuf only after B1-preceding
    // code; gbuf next written after B1 of t+1 which update threads also reach.
  }
}

// ---------------- decoder LSTM (x == h, folded weights) ----------------
__global__ __launch_bounds__(1024) void dec_kernel(
    const int* __restrict__ slen,
    const float* __restrict__ Wdc, const float* __restrict__ bdc,
    const float* __restrict__ h_all, const float* __restrict__ cT,
    float* __restrict__ h2_all)
{
  const int tid = threadIdx.x;
  const int grp = blockIdx.x & 7, slice = blockIdx.x >> 3;
  const int rp = tid >> 4, kc = tid & 15;
  const int j = ((rp >> 4) << 8) + slice*EPT_ + (rp & 15);
  float4 w0 = *(const float4*)(Wdc + (size_t)j*256 +   0 + kc*4);
  float4 w1 = *(const float4*)(Wdc + (size_t)j*256 +  64 + kc*4);
  float4 w2 = *(const float4*)(Wdc + (size_t)j*256 + 128 + kc*4);
  float4 w3 = *(const float4*)(Wdc + (size_t)j*256 + 192 + kc*4);
  float cbv = bdc[j];

  __shared__ float hbuf[4][256];
  __shared__ float gbuf[4][64];

  const int ub = tid >> 4, ue = tid & 15;
  float creg = 0.f; int myb = 0;
  if (tid < 64){ myb = grp + 8*ub; creg = cT[myb*H_ + slice*EPT_ + ue]; }

  const int tb = tid >> 7, kp = tid & 127;
  const int stage_b = grp + 8*tb;
  int stage_len = 1;
  if (tid < 512) stage_len = slen[stage_b];

  for (int s = 0; s < L_; ++s){
    if (tid < 512){
      if (s == 0){
        // h_all fully written by completed enc kernel: plain load OK
        *(float2*)&hbuf[tb][kp*2] =
            *(const float2*)(h_all + ((size_t)(stage_len-1)*B_ + stage_b)*H_ + kp*2);
      } else {
        *(float2*)&hbuf[tb][kp*2] =
            poll8(h2_all + ((size_t)(s-1)*B_ + stage_b)*H_ + kp*2);
      }
    }
    __syncthreads();  // B1

#pragma unroll
    for (int i = 0; i < 4; ++i){
      float4 h0 = *(const float4*)&hbuf[i][       kc*4];
      float4 h1 = *(const float4*)&hbuf[i][ 64 + kc*4];
      float4 h2 = *(const float4*)&hbuf[i][128 + kc*4];
      float4 h3 = *(const float4*)&hbuf[i][192 + kc*4];
      float a = dot4(w0,h0) + dot4(w1,h1) + dot4(w2,h2) + dot4(w3,h3);
#pragma unroll
      for (int off = 1; off < 16; off <<= 1) a += __shfl_xor(a, off);
      if (kc == 0) gbuf[i][rp] = a + cbv;
    }
    __syncthreads();  // B2

    if (tid < 64){
      float gi = gbuf[ub][      ue];
      float gf = gbuf[ub][16 + ue];
      float gg = gbuf[ub][32 + ue];
      float go = gbuf[ub][48 + ue];
      creg = sig_fast(gf)*creg + sig_fast(gi)*tanh_fast(gg);
      float h = sig_fast(go)*tanh_fast(creg);
      __hip_atomic_store(h2_all + ((size_t)s*B_ + myb)*H_ + slice*EPT_ + ue, h,
                         __ATOMIC_RELAXED, __HIP_MEMORY_SCOPE_AGENT);
    }
  }
}

// ---------------- kproj = masked(enc) @ Wk + bk ----------------
__global__ __launch_bounds__(256) void kproj_kernel(
    const float* __restrict__ h_all, const int* __restrict__ slen,
    const float* __restrict__ Wk, const float* __restrict__ bk,
    float* __restrict__ kp)
{
  __shared__ float wk[256*64];
  const int tid = threadIdx.x;
  const int b = blockIdx.x >> 4, tc = blockIdx.x & 15;
  const int t0 = tc*128;
#pragma unroll
  for (int i=0;i<16;i++){
    int idx = tid + i*256;
    *(float4*)(&wk[idx*4]) = *(const float4*)(Wk + idx*4);
  }
  __syncthreads();
  const int tp = tid>>2, mc = (tid&3)*16;
  const int ta = t0 + tp*2, tb = ta+1;
  const int len = slen[b];
  const bool va = ta < len, vb = tb < len;
  const float* ha = h_all + ((size_t)ta*B_ + b)*H_;
  const float* hb = h_all + ((size_t)tb*B_ + b)*H_;
  float4 A[4], Bv[4];
#pragma unroll
  for (int u=0;u<4;u++){ A[u].x=A[u].y=A[u].z=A[u].w=0.f; Bv[u]=A[u]; }

  for (int k4=0;k4<64;k4++){
    float xa[4], xb[4];
    if (va){ float4 v = *(const float4*)(ha + k4*4); xa[0]=v.x; xa[1]=v.y; xa[2]=v.z; xa[3]=v.w; }
    else   { xa[0]=xa[1]=xa[2]=xa[3]=0.f; }
    if (vb){ float4 v = *(const float4*)(hb + k4*4); xb[0]=v.x; xb[1]=v.y; xb[2]=v.z; xb[3]=v.w; }
    else   { xb[0]=xb[1]=xb[2]=xb[3]=0.f; }
#pragma unroll
    for (int jj=0;jj<4;jj++){
      const float* wr = &wk[(k4*4+jj)*64 + mc];
#pragma unroll
      for (int u=0;u<4;u++){
        float4 wv = *(const float4*)(wr + u*4);
        A[u].x  = fmaf(xa[jj],wv.x,A[u].x);  A[u].y  = fmaf(xa[jj],wv.y,A[u].y);
        A[u].z  = fmaf(xa[jj],wv.z,A[u].z);  A[u].w  = fmaf(xa[jj],wv.w,A[u].w);
        Bv[u].x = fmaf(xb[jj],wv.x,Bv[u].x); Bv[u].y = fmaf(xb[jj],wv.y,Bv[u].y);
        Bv[u].z = fmaf(xb[jj],wv.z,Bv[u].z); Bv[u].w = fmaf(xb[jj],wv.w,Bv[u].w);
      }
    }
  }
#pragma unroll
  for (int u=0;u<4;u++){
    float4 bkv = *(const float4*)(bk + mc + u*4);
    float4 ra, rb;
    ra.x = va ? A[u].x+bkv.x : bkv.x;  ra.y = va ? A[u].y+bkv.y : bkv.y;
    ra.z = va ? A[u].z+bkv.z : bkv.z;  ra.w = va ? A[u].w+bkv.w : bkv.w;
    rb.x = vb ? Bv[u].x+bkv.x : bkv.x; rb.y = vb ? Bv[u].y+bkv.y : bkv.y;
    rb.z = vb ? Bv[u].z+bkv.z : bkv.z; rb.w = vb ? Bv[u].w+bkv.w : bkv.w;
    *(float4*)(kp + ((size_t)b*T_+ta)*M_ + mc + u*4) = ra;
    *(float4*)(kp + ((size_t)b*T_+tb)*M_ + mc + u*4) = rb;
  }
}

// ---------------- attention ----------------
__global__ __launch_bounds__(256) void attn_kernel(
    const float* __restrict__ h2_all, const float* __restrict__ kp,
    const float* __restrict__ WqT, const float* __restrict__ bq,
    const int* __restrict__ slen, float* __restrict__ out)
{
  const int tid = threadIdx.x;
  const int b = blockIdx.x >> 5, scg = blockIdx.x & 31;
  const int s0 = scg*8;
  __shared__ float qL[8][64];
  __shared__ float red[8][4];
  const int wid = tid>>6, lane = tid&63;

  { // q = h2 @ Wq + bq
    const int jj = tid>>5, mh = tid&31;
    const float* hr = h2_all + ((size_t)(s0+jj)*B_ + b)*H_;
    const float* wa = WqT + (size_t)mh*256;
    const float* wb = WqT + (size_t)(mh+32)*256;
    float a0=0.f, a1=0.f;
    for (int k4=0;k4<64;k4++){
      float4 h4 = *(const float4*)(hr + k4*4);
      float4 v0 = *(const float4*)(wa + k4*4);
      float4 v1 = *(const float4*)(wb + k4*4);
      a0 += dot4(h4,v0);
      a1 += dot4(h4,v1);
    }
    qL[jj][mh]    = a0 + bq[mh];
    qL[jj][mh+32] = a1 + bq[mh+32];
  }
  __syncthreads();

  const int len = slen[b];
  float sc_[8][8];
#pragma unroll
  for (int ti=0; ti<8; ti++){
    const int t = ti*256 + tid;
    const float* kr = kp + ((size_t)b*T_ + t)*M_;
    float tmp[8];
#pragma unroll
    for (int jj=0;jj<8;jj++) tmp[jj]=0.f;
#pragma unroll
    for (int u4=0; u4<4; u4++){
      float4 k0 = *(const float4*)(kr + u4*16);
      float4 k1 = *(const float4*)(kr + u4*16 + 4);
      float4 k2 = *(const float4*)(kr + u4*16 + 8);
      float4 k3 = *(const float4*)(kr + u4*16 + 12);
#pragma unroll
      for (int jj=0;jj<8;jj++){
        const float4* q4 = (const float4*)&qL[jj][u4*16];
        tmp[jj] += dot4(k0,q4[0]) + dot4(k1,q4[1]) + dot4(k2,q4[2]) + dot4(k3,q4[3]);
      }
    }
    float bias = (t<len) ? 0.f : -1e9f;
#pragma unroll
    for (int jj=0;jj<8;jj++) sc_[ti][jj] = fmaf(tmp[jj], 0.125f, bias);
  }

  float mx[8];
#pragma unroll
  for (int jj=0;jj<8;jj++){
    float m = sc_[0][jj];
#pragma unroll
    for (int ti=1;ti<8;ti++) m = fmaxf(m, sc_[ti][jj]);
#pragma unroll
    for (int off=1; off<64; off<<=1) m = fmaxf(m, __shfl_xor(m, off));
    if (lane==0) red[jj][wid] = m;
  }
  __syncthreads();
#pragma unroll
  for (int jj=0;jj<8;jj++)
    mx[jj] = fmaxf(fmaxf(red[jj][0],red[jj][1]), fmaxf(red[jj][2],red[jj][3]));
  __syncthreads();
#pragma unroll
  for (int jj=0;jj<8;jj++){
    float s = 0.f;
#pragma unroll
    for (int ti=0;ti<8;ti++){
      float e = __expf(sc_[ti][jj] - mx[jj]);
      sc_[ti][jj] = e;
      s += e;
    }
#pragma unroll
    for (int off=1; off<64; off<<=1) s += __shfl_xor(s, off);
    if (lane==0) red[jj][wid] = s;
  }
  __syncthreads();
#pragma unroll
  for (int jj=0;jj<8;jj++){
    float r = 1.f/(red[jj][0]+red[jj][1]+red[jj][2]+red[jj][3]);
    float* o = out + ((size_t)b*L_ + s0 + jj)*T_;
#pragma unroll
    for (int ti=0;ti<8;ti++) o[ti*256 + tid] = sc_[ti][jj]*r;
  }
}

// ---------------- host ----------------
extern "C" void kernel_launch(void* const* d_in, const int* in_sizes, int n_in,
                              void* d_out, int out_size, void* d_ws, size_t ws_size,
                              hipStream_t stream) {
  (void)in_sizes; (void)n_in; (void)out_size;
  const float* seq  = (const float*)d_in[0];
  const int*   slen = (const int*)  d_in[1];
  const float* Wp   = (const float*)d_in[3];
  const float* bp   = (const float*)d_in[4];
  const float* Wihe = (const float*)d_in[5];
  const float* Whhe = (const float*)d_in[6];
  const float* bihe = (const float*)d_in[7];
  const float* bhhe = (const float*)d_in[8];
  const float* Wihd = (const float*)d_in[9];
  const float* Whhd = (const float*)d_in[10];
  const float* bihd = (const float*)d_in[11];
  const float* bhhd = (const float*)d_in[12];
  const float* Wq   = (const float*)d_in[13];
  const float* bq   = (const float*)d_in[14];
  const float* Wk   = (const float*)d_in[15];
  const float* bk   = (const float*)d_in[16];
  float* out = (float*)d_out;

  char* p = (char*)d_ws;
  auto take = [&](size_t bytes)->char* {
    char* r = p; p += (bytes + 255) & ~(size_t)255; return r;
  };
  float* h2_all = (float*)take((size_t)L_*B_*H_*4);          // 8 MB
  float* kproj  = (float*)take((size_t)B_*T_*M_*4);          // 16 MB
  float* cT     = (float*)take((size_t)B_*H_*4);
  float* W_dc   = (float*)take((size_t)G4_*H_*4);            // 1 MB
  float* Wc0    = (float*)take(G4_*4);
  float* Wc1    = (float*)take(G4_*4);
  float* bc     = (float*)take(G4_*4);
  float* b_dc   = (float*)take(G4_*4);
  float* WqT    = (float*)take((size_t)M_*H_*4);

  size_t used = (size_t)(p - (char*)d_ws);
  float* h_all;
  if (ws_size >= used + (size_t)T_*B_*H_*4) {
    h_all = (float*)take((size_t)T_*B_*H_*4);                // 64 MB
  } else {
    h_all = out;  // d_out is exactly T_*B_*H_ floats; dead before attn writes
  }

  // sentinel-fill the sequenced state buffers (consumers poll data directly)
  hipMemsetAsync(h_all,  0xFF, (size_t)T_*B_*H_*4, stream);
  hipMemsetAsync(h2_all, 0xFF, (size_t)L_*B_*H_*4, stream);

  prep_wdc  <<<G4_*H_/256, 256, 0, stream>>>(Wihd, Whhd, W_dc);
  prep_small<<<68, 256, 0, stream>>>(Wp, bp, Wihe, bihe, bhhe, bihd, bhhd, Wq,
                                     Wc0, Wc1, bc, b_dc, WqT);
  enc_kernel<<<NG_*NSL_, 1024, 0, stream>>>(seq, slen, Whhe, Wc0, Wc1, bc,
                                            h_all, cT);
  kproj_kernel<<<B_*16, 256, 0, stream>>>(h_all, slen, Wk, bk, kproj);
  dec_kernel<<<NG_*NSL_, 1024, 0, stream>>>(slen, W_dc, b_dc, h_all, cT, h2_all);
  attn_kernel<<<B_*32, 256, 0, stream>>>(h2_all, kproj, WqT, bq, slen, out);
}

// Round 4
// 6799.422 us; speedup vs baseline: 2.3013x; 1.0994x over previous
//
#include <hip/hip_runtime.h>
#include <stdint.h>

#define B_ 32
#define T_ 2048
#define H_ 256
#define M_ 64
#define L_ 256
#define G4_ 1024     // 4*H gate rows

#define NG_ 8        // batch groups (4 batches each)
#define NSL_ 16      // hidden slices per group
#define EPT_ 16      // h elements per slice
#define RING_ 8      // ring slots (slot = t & 7); reuse distance proven safe (>=2)

__device__ __forceinline__ float sig_fast(float x){ return 1.f/(1.f+__expf(-x)); }
__device__ __forceinline__ float tanh_fast(float x){ return 2.f/(1.f+__expf(-2.f*x)) - 1.f; }
__device__ __forceinline__ float dot4(float4 a, float4 b){
  return fmaf(a.x,b.x, fmaf(a.y,b.y, fmaf(a.z,b.z, a.w*b.w)));
}

// ---------------- prep kernels ----------------
__global__ void prep_wdc(const float* __restrict__ a, const float* __restrict__ b,
                         float* __restrict__ o){
  int i = blockIdx.x*256 + threadIdx.x;
  o[i] = a[i] + b[i];
}

__global__ void prep_small(const float* __restrict__ Wp, const float* __restrict__ bp,
                           const float* __restrict__ Wihe, const float* __restrict__ bihe,
                           const float* __restrict__ bhhe, const float* __restrict__ bihd,
                           const float* __restrict__ bhhd, const float* __restrict__ Wq,
                           float* __restrict__ Wc0, float* __restrict__ Wc1,
                           float* __restrict__ bc, float* __restrict__ bdc,
                           float* __restrict__ WqT){
  int idx = blockIdx.x*256 + threadIdx.x;
  if (idx < 16384){                 // WqT[m][k] = Wq[k][m]
    int m = idx >> 8, k = idx & 255;
    WqT[m*256 + k] = Wq[k*64 + m];
  } else if (idx < 16384 + 1024){   // fused input coeffs per gate row
    int j = idx - 16384;
    const float* wr = Wihe + j*256;
    float a0=0.f, a1=0.f, ab=0.f;
    for (int e=0;e<256;e++){
      float w = wr[e];
      a0 = fmaf(Wp[e],     w, a0);
      a1 = fmaf(Wp[256+e], w, a1);
      ab = fmaf(bp[e],     w, ab);
    }
    Wc0[j] = a0; Wc1[j] = a1;
    bc[j]  = ab + bihe[j] + bhhe[j];
    bdc[j] = bihd[j] + bhhd[j];
  }
}

// ---------------- encoder LSTM (persistent, L3-resident ring exchange) ----------------
__global__ __launch_bounds__(1024) void enc_kernel(
    const float* __restrict__ seq, const int* __restrict__ slen,
    const float* __restrict__ Whh,
    const float* __restrict__ Wc0, const float* __restrict__ Wc1,
    const float* __restrict__ bc,
    float* __restrict__ h_all, float* __restrict__ cT,
    unsigned long long* __restrict__ ring)
{
  const int tid = threadIdx.x;
  const int grp = blockIdx.x & 7, slice = blockIdx.x >> 3;
  const int rp = tid >> 4, kc = tid & 15;
  const int j = ((rp >> 4) << 8) + slice*EPT_ + (rp & 15);   // gate*256 + slice*16 + elem
  float4 w0 = *(const float4*)(Whh + (size_t)j*256 +   0 + kc*4);
  float4 w1 = *(const float4*)(Whh + (size_t)j*256 +  64 + kc*4);
  float4 w2 = *(const float4*)(Whh + (size_t)j*256 + 128 + kc*4);
  float4 w3 = *(const float4*)(Whh + (size_t)j*256 + 192 + kc*4);
  float c0 = Wc0[j], c1 = Wc1[j], cbv = bc[j];

  __shared__ float hbuf[4][256];
  __shared__ float sbuf[4][2];
  __shared__ float gbuf[4][64];

  const int ub = tid >> 4, ue = tid & 15;       // update mapping (tid<64)
  float creg = 0.f;
  int myb = 0, mylen = -1;
  if (tid < 64){ myb = grp + 8*ub; mylen = slen[myb]; }

  const int ib = tid >> 8, ik = tid & 255;      // consumer mapping: batch, elem
  unsigned long long* ringg = ring + (size_t)grp * (RING_*1024);

  for (int t = 0; t < T_; ++t){
    // ---- stage h_{t-1}: each thread polls its own 8B {tag,h} packet ----
    if (t == 0){
      hbuf[ib][ik] = 0.f;
    } else {
      const unsigned long long* pp = ringg + (size_t)((t-1) & (RING_-1))*1024 + tid;
      unsigned long long v;
      do { v = __hip_atomic_load(pp, __ATOMIC_RELAXED, __HIP_MEMORY_SCOPE_AGENT); }
      while ((unsigned)(v >> 32) != (unsigned)t);
      hbuf[ib][ik] = __uint_as_float((unsigned)v);
    }
    if (tid < 8) sbuf[tid>>1][tid&1] = seq[((size_t)(grp + 8*(tid>>1))*T_ + t)*2 + (tid&1)];
    __syncthreads();  // B1: hbuf/sbuf ready

    // ---- compute: one gate row per thread, K split over 16 lanes ----
#pragma unroll
    for (int i = 0; i < 4; ++i){
      float4 h0 = *(const float4*)&hbuf[i][       kc*4];
      float4 h1 = *(const float4*)&hbuf[i][ 64 + kc*4];
      float4 h2 = *(const float4*)&hbuf[i][128 + kc*4];
      float4 h3 = *(const float4*)&hbuf[i][192 + kc*4];
      float a = dot4(w0,h0) + dot4(w1,h1) + dot4(w2,h2) + dot4(w3,h3);
#pragma unroll
      for (int off = 1; off < 16; off <<= 1) a += __shfl_xor(a, off);
      if (kc == 0)
        gbuf[i][rp] = fmaf(sbuf[i][0], c0, fmaf(sbuf[i][1], c1, a + cbv));
    }
    __syncthreads();  // B2: gbuf ready

    // ---- update + publish (tid<64: 4 batches x 16 elems) ----
    if (tid < 64){
      float gi = gbuf[ub][      ue];
      float gf = gbuf[ub][16 + ue];
      float gg = gbuf[ub][32 + ue];
      float go = gbuf[ub][48 + ue];
      creg = sig_fast(gf)*creg + sig_fast(gi)*tanh_fast(gg);
      float h = sig_fast(go)*tanh_fast(creg);
      unsigned long long pk = ((unsigned long long)(unsigned)(t+1) << 32)
                            | (unsigned long long)__float_as_uint(h);
      __hip_atomic_store(ringg + (size_t)(t & (RING_-1))*1024 + ub*256 + slice*EPT_ + ue,
                         pk, __ATOMIC_RELAXED, __HIP_MEMORY_SCOPE_AGENT);
      h_all[((size_t)t*B_ + myb)*H_ + slice*EPT_ + ue] = h;   // off critical path
      if (t == mylen - 1) cT[myb*H_ + slice*EPT_ + ue] = creg;
    }
    // next-iter staging rewrites hbuf only after B1-crossing; safe without B3
  }
}

// ---------------- decoder LSTM (x == h, folded weights) ----------------
__global__ __launch_bounds__(1024) void dec_kernel(
    const int* __restrict__ slen,
    const float* __restrict__ Wdc, const float* __restrict__ bdc,
    const float* __restrict__ h_all, const float* __restrict__ cT,
    float* __restrict__ h2_all, unsigned long long* __restrict__ ring)
{
  const int tid = threadIdx.x;
  const int grp = blockIdx.x & 7, slice = blockIdx.x >> 3;
  const int rp = tid >> 4, kc = tid & 15;
  const int j = ((rp >> 4) << 8) + slice*EPT_ + (rp & 15);
  float4 w0 = *(const float4*)(Wdc + (size_t)j*256 +   0 + kc*4);
  float4 w1 = *(const float4*)(Wdc + (size_t)j*256 +  64 + kc*4);
  float4 w2 = *(const float4*)(Wdc + (size_t)j*256 + 128 + kc*4);
  float4 w3 = *(const float4*)(Wdc + (size_t)j*256 + 192 + kc*4);
  float cbv = bdc[j];

  __shared__ float hbuf[4][256];
  __shared__ float gbuf[4][64];

  const int ub = tid >> 4, ue = tid & 15;
  float creg = 0.f; int myb = 0;
  if (tid < 64){ myb = grp + 8*ub; creg = cT[myb*H_ + slice*EPT_ + ue]; }

  const int ib = tid >> 8, ik = tid & 255;
  const int stage_b = grp + 8*ib;
  const int stage_len = slen[stage_b];
  unsigned long long* ringg = ring + (size_t)grp * (RING_*1024);

  for (int s = 0; s < L_; ++s){
    if (s == 0){
      // h_all fully written by completed enc kernel: plain load OK
      hbuf[ib][ik] = h_all[((size_t)(stage_len-1)*B_ + stage_b)*H_ + ik];
    } else {
      const unsigned long long* pp = ringg + (size_t)((s-1) & (RING_-1))*1024 + tid;
      unsigned long long v;
      do { v = __hip_atomic_load(pp, __ATOMIC_RELAXED, __HIP_MEMORY_SCOPE_AGENT); }
      while ((unsigned)(v >> 32) != (unsigned)s);
      hbuf[ib][ik] = __uint_as_float((unsigned)v);
    }
    __syncthreads();  // B1

#pragma unroll
    for (int i = 0; i < 4; ++i){
      float4 h0 = *(const float4*)&hbuf[i][       kc*4];
      float4 h1 = *(const float4*)&hbuf[i][ 64 + kc*4];
      float4 h2 = *(const float4*)&hbuf[i][128 + kc*4];
      float4 h3 = *(const float4*)&hbuf[i][192 + kc*4];
      float a = dot4(w0,h0) + dot4(w1,h1) + dot4(w2,h2) + dot4(w3,h3);
#pragma unroll
      for (int off = 1; off < 16; off <<= 1) a += __shfl_xor(a, off);
      if (kc == 0) gbuf[i][rp] = a + cbv;
    }
    __syncthreads();  // B2

    if (tid < 64){
      float gi = gbuf[ub][      ue];
      float gf = gbuf[ub][16 + ue];
      float gg = gbuf[ub][32 + ue];
      float go = gbuf[ub][48 + ue];
      creg = sig_fast(gf)*creg + sig_fast(gi)*tanh_fast(gg);
      float h = sig_fast(go)*tanh_fast(creg);
      unsigned long long pk = ((unsigned long long)(unsigned)(s+1) << 32)
                            | (unsigned long long)__float_as_uint(h);
      __hip_atomic_store(ringg + (size_t)(s & (RING_-1))*1024 + ub*256 + slice*EPT_ + ue,
                         pk, __ATOMIC_RELAXED, __HIP_MEMORY_SCOPE_AGENT);
      h2_all[((size_t)s*B_ + myb)*H_ + slice*EPT_ + ue] = h;
    }
  }
}

// ---------------- kproj = masked(enc) @ Wk + bk ----------------
__global__ __launch_bounds__(256) void kproj_kernel(
    const float* __restrict__ h_all, const int* __restrict__ slen,
    const float* __restrict__ Wk, const float* __restrict__ bk,
    float* __restrict__ kp)
{
  __shared__ float wk[256*64];
  const int tid = threadIdx.x;
  const int b = blockIdx.x >> 4, tc = blockIdx.x & 15;
  const int t0 = tc*128;
#pragma unroll
  for (int i=0;i<16;i++){
    int idx = tid + i*256;
    *(float4*)(&wk[idx*4]) = *(const float4*)(Wk + idx*4);
  }
  __syncthreads();
  const int tp = tid>>2, mc = (tid&3)*16;
  const int ta = t0 + tp*2, tb = ta+1;
  const int len = slen[b];
  const bool va = ta < len, vb = tb < len;
  const float* ha = h_all + ((size_t)ta*B_ + b)*H_;
  const float* hb = h_all + ((size_t)tb*B_ + b)*H_;
  float4 A[4], Bv[4];
#pragma unroll
  for (int u=0;u<4;u++){ A[u].x=A[u].y=A[u].z=A[u].w=0.f; Bv[u]=A[u]; }

  for (int k4=0;k4<64;k4++){
    float xa[4], xb[4];
    if (va){ float4 v = *(const float4*)(ha + k4*4); xa[0]=v.x; xa[1]=v.y; xa[2]=v.z; xa[3]=v.w; }
    else   { xa[0]=xa[1]=xa[2]=xa[3]=0.f; }
    if (vb){ float4 v = *(const float4*)(hb + k4*4); xb[0]=v.x; xb[1]=v.y; xb[2]=v.z; xb[3]=v.w; }
    else   { xb[0]=xb[1]=xb[2]=xb[3]=0.f; }
#pragma unroll
    for (int jj=0;jj<4;jj++){
      const float* wr = &wk[(k4*4+jj)*64 + mc];
#pragma unroll
      for (int u=0;u<4;u++){
        float4 wv = *(const float4*)(wr + u*4);
        A[u].x  = fmaf(xa[jj],wv.x,A[u].x);  A[u].y  = fmaf(xa[jj],wv.y,A[u].y);
        A[u].z  = fmaf(xa[jj],wv.z,A[u].z);  A[u].w  = fmaf(xa[jj],wv.w,A[u].w);
        Bv[u].x = fmaf(xb[jj],wv.x,Bv[u].x); Bv[u].y = fmaf(xb[jj],wv.y,Bv[u].y);
        Bv[u].z = fmaf(xb[jj],wv.z,Bv[u].z); Bv[u].w = fmaf(xb[jj],wv.w,Bv[u].w);
      }
    }
  }
#pragma unroll
  for (int u=0;u<4;u++){
    float4 bkv = *(const float4*)(bk + mc + u*4);
    float4 ra, rb;
    ra.x = va ? A[u].x+bkv.x : bkv.x;  ra.y = va ? A[u].y+bkv.y : bkv.y;
    ra.z = va ? A[u].z+bkv.z : bkv.z;  ra.w = va ? A[u].w+bkv.w : bkv.w;
    rb.x = vb ? Bv[u].x+bkv.x : bkv.x; rb.y = vb ? Bv[u].y+bkv.y : bkv.y;
    rb.z = vb ? Bv[u].z+bkv.z : bkv.z; rb.w = vb ? Bv[u].w+bkv.w : bkv.w;
    *(float4*)(kp + ((size_t)b*T_+ta)*M_ + mc + u*4) = ra;
    *(float4*)(kp + ((size_t)b*T_+tb)*M_ + mc + u*4) = rb;
  }
}

// ---------------- attention ----------------
__global__ __launch_bounds__(256) void attn_kernel(
    const float* __restrict__ h2_all, const float* __restrict__ kp,
    const float* __restrict__ WqT, const float* __restrict__ bq,
    const int* __restrict__ slen, float* __restrict__ out)
{
  const int tid = threadIdx.x;
  const int b = blockIdx.x >> 5, scg = blockIdx.x & 31;
  const int s0 = scg*8;
  __shared__ float qL[8][64];
  __shared__ float red[8][4];
  const int wid = tid>>6, lane = tid&63;

  { // q = h2 @ Wq + bq
    const int jj = tid>>5, mh = tid&31;
    const float* hr = h2_all + ((size_t)(s0+jj)*B_ + b)*H_;
    const float* wa = WqT + (size_t)mh*256;
    const float* wb = WqT + (size_t)(mh+32)*256;
    float a0=0.f, a1=0.f;
    for (int k4=0;k4<64;k4++){
      float4 h4 = *(const float4*)(hr + k4*4);
      float4 v0 = *(const float4*)(wa + k4*4);
      float4 v1 = *(const float4*)(wb + k4*4);
      a0 += dot4(h4,v0);
      a1 += dot4(h4,v1);
    }
    qL[jj][mh]    = a0 + bq[mh];
    qL[jj][mh+32] = a1 + bq[mh+32];
  }
  __syncthreads();

  const int len = slen[b];
  float sc_[8][8];
#pragma unroll
  for (int ti=0; ti<8; ti++){
    const int t = ti*256 + tid;
    const float* kr = kp + ((size_t)b*T_ + t)*M_;
    float tmp[8];
#pragma unroll
    for (int jj=0;jj<8;jj++) tmp[jj]=0.f;
#pragma unroll
    for (int u4=0; u4<4; u4++){
      float4 k0 = *(const float4*)(kr + u4*16);
      float4 k1 = *(const float4*)(kr + u4*16 + 4);
      float4 k2 = *(const float4*)(kr + u4*16 + 8);
      float4 k3 = *(const float4*)(kr + u4*16 + 12);
#pragma unroll
      for (int jj=0;jj<8;jj++){
        const float4* q4 = (const float4*)&qL[jj][u4*16];
        tmp[jj] += dot4(k0,q4[0]) + dot4(k1,q4[1]) + dot4(k2,q4[2]) + dot4(k3,q4[3]);
      }
    }
    float bias = (t<len) ? 0.f : -1e9f;
#pragma unroll
    for (int jj=0;jj<8;jj++) sc_[ti][jj] = fmaf(tmp[jj], 0.125f, bias);
  }

  float mx[8];
#pragma unroll
  for (int jj=0;jj<8;jj++){
    float m = sc_[0][jj];
#pragma unroll
    for (int ti=1;ti<8;ti++) m = fmaxf(m, sc_[ti][jj]);
#pragma unroll
    for (int off=1; off<64; off<<=1) m = fmaxf(m, __shfl_xor(m, off));
    if (lane==0) red[jj][wid] = m;
  }
  __syncthreads();
#pragma unroll
  for (int jj=0;jj<8;jj++)
    mx[jj] = fmaxf(fmaxf(red[jj][0],red[jj][1]), fmaxf(red[jj][2],red[jj][3]));
  __syncthreads();
#pragma unroll
  for (int jj=0;jj<8;jj++){
    float s = 0.f;
#pragma unroll
    for (int ti=0;ti<8;ti++){
      float e = __expf(sc_[ti][jj] - mx[jj]);
      sc_[ti][jj] = e;
      s += e;
    }
#pragma unroll
    for (int off=1; off<64; off<<=1) s += __shfl_xor(s, off);
    if (lane==0) red[jj][wid] = s;
  }
  __syncthreads();
#pragma unroll
  for (int jj=0;jj<8;jj++){
    float r = 1.f/(red[jj][0]+red[jj][1]+red[jj][2]+red[jj][3]);
    float* o = out + ((size_t)b*L_ + s0 + jj)*T_;
#pragma unroll
    for (int ti=0;ti<8;ti++) o[ti*256 + tid] = sc_[ti][jj]*r;
  }
}

// ---------------- host ----------------
extern "C" void kernel_launch(void* const* d_in, const int* in_sizes, int n_in,
                              void* d_out, int out_size, void* d_ws, size_t ws_size,
                              hipStream_t stream) {
  (void)in_sizes; (void)n_in; (void)out_size;
  const float* seq  = (const float*)d_in[0];
  const int*   slen = (const int*)  d_in[1];
  const float* Wp   = (const float*)d_in[3];
  const float* bp   = (const float*)d_in[4];
  const float* Wihe = (const float*)d_in[5];
  const float* Whhe = (const float*)d_in[6];
  const float* bihe = (const float*)d_in[7];
  const float* bhhe = (const float*)d_in[8];
  const float* Wihd = (const float*)d_in[9];
  const float* Whhd = (const float*)d_in[10];
  const float* bihd = (const float*)d_in[11];
  const float* bhhd = (const float*)d_in[12];
  const float* Wq   = (const float*)d_in[13];
  const float* bq   = (const float*)d_in[14];
  const float* Wk   = (const float*)d_in[15];
  const float* bk   = (const float*)d_in[16];
  float* out = (float*)d_out;

  char* p = (char*)d_ws;
  auto take = [&](size_t bytes)->char* {
    char* r = p; p += (bytes + 255) & ~(size_t)255; return r;
  };
  float* h2_all = (float*)take((size_t)L_*B_*H_*4);          // 8 MB
  float* kproj  = (float*)take((size_t)B_*T_*M_*4);          // 16 MB
  float* cT     = (float*)take((size_t)B_*H_*4);
  float* W_dc   = (float*)take((size_t)G4_*H_*4);            // 1 MB
  float* Wc0    = (float*)take(G4_*4);
  float* Wc1    = (float*)take(G4_*4);
  float* bc     = (float*)take(G4_*4);
  float* b_dc   = (float*)take(G4_*4);
  float* WqT    = (float*)take((size_t)M_*H_*4);
  unsigned long long* ring_e = (unsigned long long*)take((size_t)NG_*RING_*1024*8); // 512 KB
  unsigned long long* ring_d = (unsigned long long*)take((size_t)NG_*RING_*1024*8); // 512 KB

  size_t used = (size_t)(p - (char*)d_ws);
  float* h_all;
  if (ws_size >= used + (size_t)T_*B_*H_*4) {
    h_all = (float*)take((size_t)T_*B_*H_*4);                // 64 MB
  } else {
    h_all = out;  // d_out is exactly T_*B_*H_ floats; dead before attn writes
  }

  // zero the tag rings (tags are 1..T so 0 never matches)
  hipMemsetAsync(ring_e, 0, (size_t)NG_*RING_*1024*8, stream);
  hipMemsetAsync(ring_d, 0, (size_t)NG_*RING_*1024*8, stream);

  prep_wdc  <<<G4_*H_/256, 256, 0, stream>>>(Wihd, Whhd, W_dc);
  prep_small<<<68, 256, 0, stream>>>(Wp, bp, Wihe, bihe, bhhe, bihd, bhhd, Wq,
                                     Wc0, Wc1, bc, b_dc, WqT);
  enc_kernel<<<NG_*NSL_, 1024, 0, stream>>>(seq, slen, Whhe, Wc0, Wc1, bc,
                                            h_all, cT, ring_e);
  kproj_kernel<<<B_*16, 256, 0, stream>>>(h_all, slen, Wk, bk, kproj);
  dec_kernel<<<NG_*NSL_, 1024, 0, stream>>>(slen, W_dc, b_dc, h_all, cT,
                                            h2_all, ring_d);
  attn_kernel<<<B_*32, 256, 0, stream>>>(h2_all, kproj, WqT, bq, slen, out);
}